// Round 1
// baseline (152.447 us; speedup 1.0000x reference)
//
#include <hip/hip_runtime.h>
#include <hip/hip_bf16.h>

#define Nn 302
#define Tt 2048
#define TEx 2080
#define Kk 33
#define ODOR 16
#define DTc 0.2f
#define NT (Nn*Tt)
#define NMT 19          // m tiles of 16 (304 rows)

typedef __attribute__((ext_vector_type(8))) short short8;
typedef __attribute__((ext_vector_type(4))) float f32x4;

__device__ __forceinline__ unsigned short f2bu(float x){ __hip_bfloat16 h = __float2bfloat16(x); unsigned short u; __builtin_memcpy(&u, &h, 2); return u; }

// ALL inputs/outputs are float32 (proven: R2/R3/R6 passed running f32 bodies).
__device__ __forceinline__ void ld8(const float* p, size_t i, float* v){
    float4 a = *(const float4*)(p + i);
    float4 b = *(const float4*)(p + i + 4);
    v[0]=a.x; v[1]=a.y; v[2]=a.z; v[3]=a.w;
    v[4]=b.x; v[5]=b.y; v[6]=b.z; v[7]=b.w;
}
__device__ __forceinline__ void st8(float* p, size_t i, const float* v){
    *(float4*)(p + i)     = make_float4(v[0],v[1],v[2],v[3]);
    *(float4*)(p + i + 4) = make_float4(v[4],v[5],v[6],v[7]);
}

// out regions (x NT f32): 0 mnv, 1 fluor, 2 mu_v, 3 logvar, 4 sample_v,
// 5 calcium_act, 6 mu_calcium, 7 recurrent_in, 8 sensory_input
__device__ __forceinline__ float* region(void* outv, int r){
    return (float*)outv + (size_t)r * NT;
}

// ============ Kernel A: encode + dwconv + pointwise + fused calcium scan ============
__global__ __launch_bounds__(256) void kA(
    const float* __restrict__ fr, const float* __restrict__ odor,
    const float* __restrict__ eps,
    const float* __restrict__ Wenc, const float* __restrict__ benc,
    const float* __restrict__ mask,
    const float* __restrict__ Wmf, const float* __restrict__ Wms,
    const float* __restrict__ bmu,
    const float* __restrict__ Wlf, const float* __restrict__ Wls,
    const float* __restrict__ blv,
    const float* __restrict__ waff, const float* __restrict__ baff,
    const float* __restrict__ fft, const float* __restrict__ scal,
    const float* __restrict__ shft, const float* __restrict__ ctau,
    void* outv)
{
    __shared__ float frs[TEx];
    __shared__ float ses[TEx];
    __shared__ float Bsc[256];
    __shared__ float Psc[256];
    __shared__ float wv[4*Kk + ODOR];

    const int n = blockIdx.x;
    const int tid = threadIdx.x;
    float* wmf_s = wv;        float* wms_s = wv + Kk;
    float* wlf_s = wv + 2*Kk; float* wls_s = wv + 3*Kk;
    float* wenc_s = wv + 4*Kk;

    if (tid < Kk){
        wmf_s[tid] = Wmf[n*Kk+tid];
        wms_s[tid] = Wms[n*Kk+tid];
        wlf_s[tid] = Wlf[n*Kk+tid];
        wls_s[tid] = Wls[n*Kk+tid];
    }
    if (tid < ODOR) wenc_s[tid] = Wenc[n*ODOR+tid];

    for (int c = tid; c < TEx/8; c += 256){
        float v[8];
        ld8(fr, (size_t)n*TEx + c*8, v);
        #pragma unroll
        for (int j = 0; j < 8; j++) frs[c*8+j] = v[j];
    }
    __syncthreads();

    const float benc_f = benc[n];
    const float mask_f = mask[n];
    for (int c = tid; c < TEx/8; c += 256){
        float acc[8];
        #pragma unroll
        for (int j = 0; j < 8; j++) acc[j] = benc_f;
        #pragma unroll
        for (int o = 0; o < ODOR; o++){
            float v[8];
            ld8(odor, (size_t)o*TEx + c*8, v);
            #pragma unroll
            for (int j = 0; j < 8; j++) acc[j] = fmaf(wenc_s[o], v[j], acc[j]);
        }
        #pragma unroll
        for (int j = 0; j < 8; j++) ses[c*8+j] = mask_f*acc[j];
    }
    __syncthreads();

    const float bmu_f  = bmu[n];
    const float blv_f  = blv[n];
    const float waff_f = waff[n];
    const float baff_f = baff[n];

    const int t0 = tid*8;
    float xf[40], xs[40];
    #pragma unroll
    for (int i = 0; i < 10; i++){
        float4 a = *(const float4*)&frs[t0 + 4*i];
        xf[4*i]=a.x; xf[4*i+1]=a.y; xf[4*i+2]=a.z; xf[4*i+3]=a.w;
        float4 b = *(const float4*)&ses[t0 + 4*i];
        xs[4*i]=b.x; xs[4*i+1]=b.y; xs[4*i+2]=b.z; xs[4*i+3]=b.w;
    }

    float aMu[8], aLv[8];
    #pragma unroll
    for (int j = 0; j < 8; j++){ aMu[j]=bmu_f; aLv[j]=blv_f; }
    #pragma unroll
    for (int k = 0; k < Kk; k++){
        float wf=wmf_s[k], wsn=wms_s[k], vf=wlf_s[k], vsn=wls_s[k];
        #pragma unroll
        for (int j = 0; j < 8; j++){
            aMu[j] = fmaf(xf[j+k], wf, fmaf(xs[j+k], wsn, aMu[j]));
            aLv[j] = fmaf(xf[j+k], vf, fmaf(xs[j+k], vsn, aLv[j]));
        }
    }

    const size_t base = (size_t)n*Tt + t0;
    float ev[8];
    ld8(eps, base, ev);

    float smp[8], cav[8], siv[8];
    #pragma unroll
    for (int j = 0; j < 8; j++){
        float s = aMu[j] + expf(0.5f*aLv[j])*ev[j];
        smp[j] = s;
        float x = waff_f*s + baff_f;
        cav[j] = (x > 20.f) ? x : log1pf(expf(x));
        siv[j] = ses[t0 + j + 16];   // crop = 16
    }

    st8(region(outv,2), base, aMu);
    st8(region(outv,3), base, aLv);
    st8(region(outv,4), base, smp);
    st8(region(outv,5), base, cav);
    st8(region(outv,8), base, siv);

    // ---- calcium IIR scan: c[-1]=init, c[t]=decay*c[t-1]+ca[t] ----
    const float sc = scal[n];
    const float sh = shft[n];
    const float ct = ctau[n];
    const float decay = expf(-DTc/ct);

    float b = 0.f;
    #pragma unroll
    for (int j = 0; j < 8; j++) b = fmaf(decay, b, cav[j]);
    Bsc[tid] = b;
    __syncthreads();

    if (tid < 64){
        const float d2 = decay*decay, d4 = d2*d2, d8 = d4*d4;
        const float d16 = d8*d8, d32 = d16*d16;
        float g0=Bsc[4*tid], g1=Bsc[4*tid+1], g2=Bsc[4*tid+2], g3=Bsc[4*tid+3];
        float G = fmaf(d8, fmaf(d8, fmaf(d8, g0, g1), g2), g3);   // 32-elem block value
        float S = G, pw = d32;
        #pragma unroll
        for (int off = 1; off < 64; off <<= 1){
            float up = __shfl_up(S, off, 64);
            if (tid >= off) S = fmaf(pw, up, S);
            pw = pw*pw;
        }
        float E = __shfl_up(S, 1, 64);                            // exclusive prefix
        if (tid == 0) E = 0.f;
        const float init = (fft[(size_t)n*Tt] - sh)/sc;
        float P = fmaf(init, __powf(d32, (float)tid), E);         // carry entering chunk 4*tid
        #pragma unroll
        for (int j = 0; j < 4; j++){ Psc[4*tid+j] = P; P = fmaf(d8, P, Bsc[4*tid+j]); }
    }
    __syncthreads();

    float c = Psc[tid];
    float mc[8], fl[8];
    #pragma unroll
    for (int j = 0; j < 8; j++){
        c = fmaf(decay, c, cav[j]);
        mc[j] = c;
        fl[j] = fmaf(sc, c, sh);
    }
    st8(region(outv,6), base, mc);
    st8(region(outv,1), base, fl);
}

// ============ Kernel GF: fused bf16-convert + MFMA GEMM + f32 epilogue ============
// recurrent_in = W_chem @ relu(sv) + W_elec @ sv + si, computed directly from
// f32 sources (no workspace, no transpose-pass kernel).
// grid (32, NMT), 256 threads = 4 waves; wave w -> nt = bx*4+w, m-tile = by.
// A frags (shared by the 4 waves) are built once per block into LDS:
//   slot s = (pass*10 + kb)*64 + l ; value = W[by*16 + (l&15)][kb*32 + (l>>4)*8 + j]
//   pass 0 = W_chem (paired with relu(sv)), pass 1 = W_elec (raw sv).
// B frags are read straight from sv in fragment order:
//   lane l, kb, j -> sv[kb*32 + (l>>4)*8 + j][(bx*4+w)*16 + (l&15)]
//   (fixed (kb,j): 4 k-rows x 16 consecutive t cols = 4 coalesced 64B segments, L2-hot)
__global__ __launch_bounds__(256) void kGF(
    const float* __restrict__ Wch, const float* __restrict__ Wel,
    const float* __restrict__ bias, const float* __restrict__ tau,
    void* outv)
{
    __shared__ unsigned short As[20*64*8];   // 20 KB: 10 kb x {chem, elec}
    __shared__ float C[16][68];

    const int tid = threadIdx.x;
    const int wave = tid >> 6, lane = tid & 63;
    const int ln = lane & 15, quad = lane >> 4;
    const int bx = blockIdx.x, by = blockIdx.y;

    // ---- build A fragments cooperatively (both passes), zero-padded ----
    for (int s = tid; s < 20*64; s += 256){
        const int kbp = s >> 6, l = s & 63;
        const int pass = kbp / 10, kb = kbp - pass*10;
        const int lm = l & 15, lq = l >> 4;
        const int m = by*16 + lm;
        const int k0 = kb*32 + lq*8;
        const float* W = pass ? Wel : Wch;
        unsigned short v[8];
        #pragma unroll
        for (int j = 0; j < 8; j++){
            const int k = k0 + j;
            float x = (m < Nn && k < Nn) ? W[(size_t)m*Nn + k] : 0.f;
            v[j] = f2bu(x);
        }
        *(uint4*)(As + (size_t)s*8) = make_uint4(
            (unsigned)v[0]|((unsigned)v[1]<<16), (unsigned)v[2]|((unsigned)v[3]<<16),
            (unsigned)v[4]|((unsigned)v[5]<<16), (unsigned)v[6]|((unsigned)v[7]<<16));
    }
    __syncthreads();

    const float* o_sv = region(outv, 4);
    const int t = (bx*4 + wave)*16 + ln;

    // two independent accumulator chains (chem/elec) for MFMA ILP
    f32x4 accC = {0.f,0.f,0.f,0.f};
    f32x4 accE = {0.f,0.f,0.f,0.f};
    #pragma unroll
    for (int kb = 0; kb < 10; kb++){
        const int k0 = kb*32 + quad*8;
        short8 ac = *(const short8*)(As + ((size_t)( kb     *64 + lane))*8);
        short8 ae = *(const short8*)(As + ((size_t)((10+kb)*64 + lane))*8);
        float bv[8];
        #pragma unroll
        for (int j = 0; j < 8; j++){
            int k = k0 + j;
            if (k > Nn-1) k = Nn-1;          // clamp: A is zero there, value irrelevant
            bv[j] = o_sv[(size_t)k*Tt + t];
        }
        short8 bc, be;
        #pragma unroll
        for (int j = 0; j < 8; j++){
            be[j] = (short)f2bu(bv[j]);
            bc[j] = (short)f2bu(fmaxf(bv[j], 0.f));
        }
        accC = __builtin_amdgcn_mfma_f32_16x16x32_bf16(ac, bc, accC, 0, 0, 0);
        accE = __builtin_amdgcn_mfma_f32_16x16x32_bf16(ae, be, accE, 0, 0, 0);
    }

    #pragma unroll
    for (int r = 0; r < 4; r++) C[quad*4 + r][wave*16 + ln] = accC[r] + accE[r];
    __syncthreads();

    if (tid < 128){
        const int m_loc = tid >> 3, strip = tid & 7;
        const int m = by*16 + m_loc;
        if (m < Nn){
            const float* o_si = region(outv, 8);
            float* o_mnv = region(outv, 0);
            float* o_rec = region(outv, 7);
            const int tt = bx*64 + strip*8;
            const size_t idx = (size_t)m*Tt + tt;
            float si[8], sv[8], rec[8], mnv[8];
            ld8(o_si, idx, si);
            ld8(o_sv, idx, sv);
            const float it = DTc / tau[m];
            const float bi = bias[m];
            #pragma unroll
            for (int j = 0; j < 8; j++){
                float rc = C[m_loc][strip*8 + j] + si[j];
                rec[j] = rc;
                mnv[j] = sv[j] + it*(-sv[j] + rc + bi);
            }
            st8(o_rec, idx, rec);
            st8(o_mnv, idx, mnv);
        }
    }
}

extern "C" void kernel_launch(void* const* d_in, const int* in_sizes, int n_in,
                              void* d_out, int out_size, void* d_ws, size_t ws_size,
                              hipStream_t stream) {
    const float* fr   = (const float*)d_in[0];
    const float* fft  = (const float*)d_in[1];
    const float* odor = (const float*)d_in[2];
    const float* eps  = (const float*)d_in[3];
    const float* Wenc = (const float*)d_in[4];
    const float* benc = (const float*)d_in[5];
    const float* mask = (const float*)d_in[6];
    const float* Wmf  = (const float*)d_in[7];
    const float* Wms  = (const float*)d_in[8];
    const float* bmu  = (const float*)d_in[9];
    const float* Wlf  = (const float*)d_in[10];
    const float* Wls  = (const float*)d_in[11];
    const float* blv  = (const float*)d_in[12];
    const float* Wch  = (const float*)d_in[13];
    const float* Wel  = (const float*)d_in[14];
    const float* bias = (const float*)d_in[15];
    const float* tau  = (const float*)d_in[16];
    const float* waff = (const float*)d_in[17];
    const float* baff = (const float*)d_in[18];
    const float* scal = (const float*)d_in[19];
    const float* shft = (const float*)d_in[20];
    const float* ctau = (const float*)d_in[21];

    (void)d_ws; (void)ws_size;   // workspace no longer used (kTP eliminated)

    kA<<<Nn, 256, 0, stream>>>(fr, odor, eps, Wenc, benc, mask, Wmf, Wms, bmu,
                               Wlf, Wls, blv, waff, baff, fft, scal, shft, ctau, d_out);

    kGF<<<dim3(32, NMT), 256, 0, stream>>>(Wch, Wel, bias, tau, d_out);
}

// Round 2
// 151.723 us; speedup vs baseline: 1.0048x; 1.0048x over previous
//
#include <hip/hip_runtime.h>
#include <hip/hip_bf16.h>

#define Nn 302
#define Tt 2048
#define TEx 2080
#define Kk 33
#define ODOR 16
#define DTc 0.2f
#define NT (Nn*Tt)
#define NMT 19          // m tiles of 16 (304 rows)
#define GEMMB (32*NMT)  // 608 GEMM blocks in kB

typedef __attribute__((ext_vector_type(8))) short short8;
typedef __attribute__((ext_vector_type(4))) float f32x4;

__device__ __forceinline__ unsigned short f2bu(float x){ __hip_bfloat16 h = __float2bfloat16(x); unsigned short u; __builtin_memcpy(&u, &h, 2); return u; }

// ALL inputs/outputs are float32 (proven: R2/R3/R6 passed running f32 bodies).
__device__ __forceinline__ void ld8(const float* p, size_t i, float* v){
    float4 a = *(const float4*)(p + i);
    float4 b = *(const float4*)(p + i + 4);
    v[0]=a.x; v[1]=a.y; v[2]=a.z; v[3]=a.w;
    v[4]=b.x; v[5]=b.y; v[6]=b.z; v[7]=b.w;
}
__device__ __forceinline__ void st8(float* p, size_t i, const float* v){
    *(float4*)(p + i)     = make_float4(v[0],v[1],v[2],v[3]);
    *(float4*)(p + i + 4) = make_float4(v[4],v[5],v[6],v[7]);
}

// out regions (x NT f32): 0 mnv, 1 fluor, 2 mu_v, 3 logvar, 4 sample_v,
// 5 calcium_act, 6 mu_calcium, 7 recurrent_in, 8 sensory_input
__device__ __forceinline__ float* region(void* outv, int r){
    return (float*)outv + (size_t)r * NT;
}

// ============ Kernel A1: encode + dwconv + pointwise (t-split, no scan) ============
// grid (302, 2): block (n, tc) owns output cols [tc*1024, tc*1024+1024).
// LDS window of 1056 covers conv taps (k<=32) and the crop-16 sensory slice.
__global__ __launch_bounds__(256) void kA1(
    const float* __restrict__ fr, const float* __restrict__ odor,
    const float* __restrict__ eps,
    const float* __restrict__ Wenc, const float* __restrict__ benc,
    const float* __restrict__ mask,
    const float* __restrict__ Wmf, const float* __restrict__ Wms,
    const float* __restrict__ bmu,
    const float* __restrict__ Wlf, const float* __restrict__ Wls,
    const float* __restrict__ blv,
    const float* __restrict__ waff, const float* __restrict__ baff,
    void* outv)
{
    __shared__ float frs[1056];
    __shared__ float sess[1056];
    __shared__ float wv[4*Kk + ODOR];

    const int n = blockIdx.x;
    const int c0 = blockIdx.y * 1024;
    const int tid = threadIdx.x;
    float* wmf_s = wv;        float* wms_s = wv + Kk;
    float* wlf_s = wv + 2*Kk; float* wls_s = wv + 3*Kk;
    float* wenc_s = wv + 4*Kk;

    if (tid < Kk){
        wmf_s[tid] = Wmf[n*Kk+tid];
        wms_s[tid] = Wms[n*Kk+tid];
        wlf_s[tid] = Wlf[n*Kk+tid];
        wls_s[tid] = Wls[n*Kk+tid];
    }
    if (tid < ODOR) wenc_s[tid] = Wenc[n*ODOR+tid];

    for (int i = tid; i < 1056; i += 256)
        frs[i] = fr[(size_t)n*TEx + c0 + i];
    __syncthreads();

    const float benc_f = benc[n];
    const float mask_f = mask[n];
    for (int i = tid; i < 1056; i += 256){
        float acc = benc_f;
        #pragma unroll
        for (int o = 0; o < ODOR; o++)
            acc = fmaf(wenc_s[o], odor[(size_t)o*TEx + c0 + i], acc);
        sess[i] = mask_f*acc;
    }
    __syncthreads();

    const float bmu_f  = bmu[n];
    const float blv_f  = blv[n];
    const float waff_f = waff[n];
    const float baff_f = baff[n];

    const int local = tid*4;
    float xf[37], xs[37];
    #pragma unroll
    for (int i = 0; i < 9; i++){
        float4 a = *(const float4*)&frs[local + 4*i];
        xf[4*i]=a.x; xf[4*i+1]=a.y; xf[4*i+2]=a.z; xf[4*i+3]=a.w;
        float4 b = *(const float4*)&sess[local + 4*i];
        xs[4*i]=b.x; xs[4*i+1]=b.y; xs[4*i+2]=b.z; xs[4*i+3]=b.w;
    }
    xf[36] = frs[local + 36];
    xs[36] = sess[local + 36];

    float aMu[4], aLv[4];
    #pragma unroll
    for (int j = 0; j < 4; j++){ aMu[j]=bmu_f; aLv[j]=blv_f; }
    #pragma unroll
    for (int k = 0; k < Kk; k++){
        float wf=wmf_s[k], wsn=wms_s[k], vf=wlf_s[k], vsn=wls_s[k];
        #pragma unroll
        for (int j = 0; j < 4; j++){
            aMu[j] = fmaf(xf[j+k], wf, fmaf(xs[j+k], wsn, aMu[j]));
            aLv[j] = fmaf(xf[j+k], vf, fmaf(xs[j+k], vsn, aLv[j]));
        }
    }

    const size_t base = (size_t)n*Tt + c0 + local;
    float4 ev = *(const float4*)(eps + base);
    float evv[4] = {ev.x, ev.y, ev.z, ev.w};

    float smp[4], cav[4], siv[4];
    #pragma unroll
    for (int j = 0; j < 4; j++){
        float s = aMu[j] + expf(0.5f*aLv[j])*evv[j];
        smp[j] = s;
        float x = waff_f*s + baff_f;
        cav[j] = (x > 20.f) ? x : log1pf(expf(x));
        siv[j] = sess[local + j + 16];   // crop = 16
    }

    *(float4*)(region(outv,2) + base) = make_float4(aMu[0],aMu[1],aMu[2],aMu[3]);
    *(float4*)(region(outv,3) + base) = make_float4(aLv[0],aLv[1],aLv[2],aLv[3]);
    *(float4*)(region(outv,4) + base) = make_float4(smp[0],smp[1],smp[2],smp[3]);
    *(float4*)(region(outv,5) + base) = make_float4(cav[0],cav[1],cav[2],cav[3]);
    *(float4*)(region(outv,8) + base) = make_float4(siv[0],siv[1],siv[2],siv[3]);
}

// ============ Kernel B: fused {MFMA GEMM + epilogue} ∪ {calcium IIR scan} ============
// grid = GEMMB + Nn blocks of 256.
//   blockIdx.x <  GEMMB : GEMM block  (bx = b&31 -> t-tile, by = b>>5 -> m-tile)
//   blockIdx.x >= GEMMB : scan block for neuron n = blockIdx.x - GEMMB
__global__ __launch_bounds__(256) void kB(
    const float* __restrict__ Wch, const float* __restrict__ Wel,
    const float* __restrict__ bias, const float* __restrict__ tau,
    const float* __restrict__ fft, const float* __restrict__ scal,
    const float* __restrict__ shft, const float* __restrict__ ctau,
    void* outv)
{
    // union'd LDS: GEMM uses As(20KB)+C(4.25KB); scan uses Bsc+Psc (2KB)
    __shared__ __align__(16) char smraw[20*64*8*2 + 16*68*4];
    unsigned short* As = (unsigned short*)smraw;
    float (*C)[68] = (float(*)[68])(smraw + 20*64*8*2);
    float* Bsc = (float*)smraw;
    float* Psc = (float*)(smraw + 256*4);

    const int tid = threadIdx.x;

    if (blockIdx.x < GEMMB){
        // ---------------- GEMM branch (former kGF) ----------------
        const int wave = tid >> 6, lane = tid & 63;
        const int ln = lane & 15, quad = lane >> 4;
        const int bx = blockIdx.x & 31, by = blockIdx.x >> 5;

        for (int s = tid; s < 20*64; s += 256){
            const int kbp = s >> 6, l = s & 63;
            const int pass = kbp / 10, kb = kbp - pass*10;
            const int lm = l & 15, lq = l >> 4;
            const int m = by*16 + lm;
            const int k0 = kb*32 + lq*8;
            const float* W = pass ? Wel : Wch;
            unsigned short v[8];
            #pragma unroll
            for (int j = 0; j < 8; j++){
                const int k = k0 + j;
                float x = (m < Nn && k < Nn) ? W[(size_t)m*Nn + k] : 0.f;
                v[j] = f2bu(x);
            }
            *(uint4*)(As + (size_t)s*8) = make_uint4(
                (unsigned)v[0]|((unsigned)v[1]<<16), (unsigned)v[2]|((unsigned)v[3]<<16),
                (unsigned)v[4]|((unsigned)v[5]<<16), (unsigned)v[6]|((unsigned)v[7]<<16));
        }
        __syncthreads();

        const float* o_sv = region(outv, 4);
        const int t = (bx*4 + wave)*16 + ln;

        f32x4 accC = {0.f,0.f,0.f,0.f};
        f32x4 accE = {0.f,0.f,0.f,0.f};
        #pragma unroll
        for (int kb = 0; kb < 10; kb++){
            const int k0 = kb*32 + quad*8;
            short8 ac = *(const short8*)(As + ((size_t)( kb     *64 + lane))*8);
            short8 ae = *(const short8*)(As + ((size_t)((10+kb)*64 + lane))*8);
            float bv[8];
            #pragma unroll
            for (int j = 0; j < 8; j++){
                int k = k0 + j;
                if (k > Nn-1) k = Nn-1;          // clamp: A is zero there, value irrelevant
                bv[j] = o_sv[(size_t)k*Tt + t];
            }
            short8 bc, be;
            #pragma unroll
            for (int j = 0; j < 8; j++){
                be[j] = (short)f2bu(bv[j]);
                bc[j] = (short)f2bu(fmaxf(bv[j], 0.f));
            }
            accC = __builtin_amdgcn_mfma_f32_16x16x32_bf16(ac, bc, accC, 0, 0, 0);
            accE = __builtin_amdgcn_mfma_f32_16x16x32_bf16(ae, be, accE, 0, 0, 0);
        }

        #pragma unroll
        for (int r = 0; r < 4; r++) C[quad*4 + r][wave*16 + ln] = accC[r] + accE[r];
        __syncthreads();

        if (tid < 128){
            const int m_loc = tid >> 3, strip = tid & 7;
            const int m = by*16 + m_loc;
            if (m < Nn){
                const float* o_si = region(outv, 8);
                float* o_mnv = region(outv, 0);
                float* o_rec = region(outv, 7);
                const int tt = bx*64 + strip*8;
                const size_t idx = (size_t)m*Tt + tt;
                float si[8], sv[8], rec[8], mnv[8];
                ld8(o_si, idx, si);
                ld8(o_sv, idx, sv);
                const float it = DTc / tau[m];
                const float bi = bias[m];
                #pragma unroll
                for (int j = 0; j < 8; j++){
                    float rc = C[m_loc][strip*8 + j] + si[j];
                    rec[j] = rc;
                    mnv[j] = sv[j] + it*(-sv[j] + rc + bi);
                }
                st8(o_rec, idx, rec);
                st8(o_mnv, idx, mnv);
            }
        }
        return;
    }

    // ---------------- scan branch: calcium IIR for neuron n ----------------
    const int n = blockIdx.x - GEMMB;
    const size_t base = (size_t)n*Tt + tid*8;

    float cav[8];
    ld8(region(outv,5), base, cav);

    const float sc = scal[n];
    const float sh = shft[n];
    const float ct = ctau[n];
    const float decay = expf(-DTc/ct);

    float b = 0.f;
    #pragma unroll
    for (int j = 0; j < 8; j++) b = fmaf(decay, b, cav[j]);
    Bsc[tid] = b;
    __syncthreads();

    if (tid < 64){
        const float d2 = decay*decay, d4 = d2*d2, d8 = d4*d4;
        const float d16 = d8*d8, d32 = d16*d16;
        float g0=Bsc[4*tid], g1=Bsc[4*tid+1], g2=Bsc[4*tid+2], g3=Bsc[4*tid+3];
        float G = fmaf(d8, fmaf(d8, fmaf(d8, g0, g1), g2), g3);   // 32-elem block value
        float S = G, pw = d32;
        #pragma unroll
        for (int off = 1; off < 64; off <<= 1){
            float up = __shfl_up(S, off, 64);
            if (tid >= off) S = fmaf(pw, up, S);
            pw = pw*pw;
        }
        float E = __shfl_up(S, 1, 64);                            // exclusive prefix
        if (tid == 0) E = 0.f;
        const float init = (fft[(size_t)n*Tt] - sh)/sc;
        float P = fmaf(init, __powf(d32, (float)tid), E);         // carry entering chunk 4*tid
        #pragma unroll
        for (int j = 0; j < 4; j++){ Psc[4*tid+j] = P; P = fmaf(d8, P, Bsc[4*tid+j]); }
    }
    __syncthreads();

    float c = Psc[tid];
    float mc[8], fl[8];
    #pragma unroll
    for (int j = 0; j < 8; j++){
        c = fmaf(decay, c, cav[j]);
        mc[j] = c;
        fl[j] = fmaf(sc, c, sh);
    }
    st8(region(outv,6), base, mc);
    st8(region(outv,1), base, fl);
}

extern "C" void kernel_launch(void* const* d_in, const int* in_sizes, int n_in,
                              void* d_out, int out_size, void* d_ws, size_t ws_size,
                              hipStream_t stream) {
    const float* fr   = (const float*)d_in[0];
    const float* fft  = (const float*)d_in[1];
    const float* odor = (const float*)d_in[2];
    const float* eps  = (const float*)d_in[3];
    const float* Wenc = (const float*)d_in[4];
    const float* benc = (const float*)d_in[5];
    const float* mask = (const float*)d_in[6];
    const float* Wmf  = (const float*)d_in[7];
    const float* Wms  = (const float*)d_in[8];
    const float* bmu  = (const float*)d_in[9];
    const float* Wlf  = (const float*)d_in[10];
    const float* Wls  = (const float*)d_in[11];
    const float* blv  = (const float*)d_in[12];
    const float* Wch  = (const float*)d_in[13];
    const float* Wel  = (const float*)d_in[14];
    const float* bias = (const float*)d_in[15];
    const float* tau  = (const float*)d_in[16];
    const float* waff = (const float*)d_in[17];
    const float* baff = (const float*)d_in[18];
    const float* scal = (const float*)d_in[19];
    const float* shft = (const float*)d_in[20];
    const float* ctau = (const float*)d_in[21];

    (void)d_ws; (void)ws_size;   // workspace unused

    kA1<<<dim3(Nn, 2), 256, 0, stream>>>(fr, odor, eps, Wenc, benc, mask,
                                         Wmf, Wms, bmu, Wlf, Wls, blv,
                                         waff, baff, d_out);

    kB<<<GEMMB + Nn, 256, 0, stream>>>(Wch, Wel, bias, tau,
                                       fft, scal, shft, ctau, d_out);
}